// Round 4
// baseline (139.582 us; speedup 1.0000x reference)
//
#include <hip/hip_runtime.h>
#include <hip/hip_bf16.h>

typedef float f32x4 __attribute__((ext_vector_type(4)));
typedef __bf16 bf16x8 __attribute__((ext_vector_type(8)));
typedef unsigned short ushort_t;

#define SEQ 2048
#define BATCH 2
#define EMS 256
#define NHEAD 8
#define HEAD 32
#define BH (BATCH*NHEAD)

static __device__ __forceinline__ ushort_t f2bfbits(float f) {
    unsigned int u = __float_as_uint(f);
    u += 0x7fffu + ((u >> 16) & 1u);   // round-to-nearest-even
    return (ushort_t)(u >> 16);
}

static __device__ __forceinline__ unsigned cvtpk(float lo, float hi) {
    unsigned r;
    asm("v_cvt_pk_bf16_f32 %0, %1, %2" : "=v"(r) : "v"(lo), "v"(hi));
    return r;
}

static __device__ __forceinline__ bf16x8 cvt8(const float* p) {
    float4 a = *reinterpret_cast<const float4*>(p);
    float4 b = *reinterpret_cast<const float4*>(p + 4);
    union { bf16x8 v; uint4 u; } x;
    x.u.x = cvtpk(a.x, a.y);
    x.u.y = cvtpk(a.z, a.w);
    x.u.z = cvtpk(b.x, b.y);
    x.u.w = cvtpk(b.z, b.w);
    return x.v;
}

// ---------------- Fused pre-pass ----------------
// Blocks [0,512): mask nonzero-scan -> 64-bit flags per (b, qtile).  Pure
// coalesced streaming (the mask's ONLY read when it is all-zero).
// Blocks [512,1280): QKV projection, 32x32 wave tiles.  V is written in
// blocked-transposed layout Vt2[bh][kblk][32d][32kin] so attn's PV loads are
// contiguous-1KB per instruction (same ideal pattern as K).
__global__ __launch_bounds__(256) void fused_pre(
    const float* __restrict__ em, const float* __restrict__ mask,
    const float* __restrict__ Wq, const float* __restrict__ bq,
    const float* __restrict__ Wk, const float* __restrict__ bk,
    const float* __restrict__ Wv, const float* __restrict__ bv,
    ushort_t* __restrict__ Qb, ushort_t* __restrict__ Kb,
    ushort_t* __restrict__ Vt2, unsigned* __restrict__ flagsG)
{
    if (blockIdx.x < 512) {
        // ---- mask scan: block = (b, qt, khalf) covers 16 rows x 1024 cols
        int fb = blockIdx.x;
        int kh = fb & 1, qt = (fb >> 1) & 127, b = fb >> 8;
        int t = threadIdx.x;
        const float* base = mask + ((size_t)b * SEQ + qt * 16) * SEQ + kh * 1024 + t * 4;
        unsigned nz = 0;
        #pragma unroll 4
        for (int it = 0; it < 16; it++) {
            float4 v = *(const float4*)(base + (size_t)it * SEQ);
            if (v.x != 0.f || v.y != 0.f || v.z != 0.f || v.w != 0.f) nz = 1;
        }
        __shared__ unsigned fl;
        if (t == 0) fl = 0;
        __syncthreads();
        if (nz) atomicOr(&fl, 1u << (t >> 3));   // 8 float4 per 32-wide k-tile
        __syncthreads();
        if (t == 0) flagsG[(b * 128 + qt) * 2 + kh] = fl;
        return;
    }

    // ---- QKV projection
    int wid = (blockIdx.x - 512) * 4 + (threadIdx.x >> 6);
    int l   = threadIdx.x & 63;
    int l15 = l & 15, lq = l >> 4;
    int rb = wid / 24, cg = wid % 24;
    int r0 = rb * 32, c0 = cg * 32;
    int sel = c0 >> 8;                       // 0=Q 1=K 2=V (uniform per wave)
    const float* W    = sel == 0 ? Wq : (sel == 1 ? Wk : Wv);
    const float* bias = sel == 0 ? bq : (sel == 1 ? bk : bv);
    int cb = c0 & 255;

    f32x4 acc[2][2];
    #pragma unroll
    for (int m = 0; m < 2; m++)
        #pragma unroll
        for (int n = 0; n < 2; n++) acc[m][n] = (f32x4){0.f, 0.f, 0.f, 0.f};

    #pragma unroll
    for (int kk = 0; kk < 8; kk++) {
        int k0 = kk * 32;
        bf16x8 af[2], bfm[2];
        #pragma unroll
        for (int m = 0; m < 2; m++)
            af[m] = cvt8(em + (size_t)(r0 + m * 16 + l15) * EMS + k0 + lq * 8);
        #pragma unroll
        for (int n = 0; n < 2; n++)
            bfm[n] = cvt8(W + (size_t)(cb + n * 16 + l15) * EMS + k0 + lq * 8);
        #pragma unroll
        for (int m = 0; m < 2; m++)
            #pragma unroll
            for (int n = 0; n < 2; n++)
                acc[m][n] = __builtin_amdgcn_mfma_f32_16x16x32_bf16(af[m], bfm[n], acc[m][n], 0, 0, 0);
    }

    float scale = (sel == 0) ? 0.17677669529663687f : 1.0f;  // 1/sqrt(32) in Q
    #pragma unroll
    for (int m = 0; m < 2; m++) {
        #pragma unroll
        for (int n = 0; n < 2; n++) {
            int c = cb + n * 16 + l15;
            float bv_ = bias[c];
            int h = c >> 5, d = c & 31;
            #pragma unroll
            for (int r = 0; r < 4; r++) {
                int row = r0 + m * 16 + lq * 4 + r;   // C/D: row=(l>>4)*4+reg, col=l&15
                int s = row >> 1, b = row & 1;
                int bh = b * NHEAD + h;
                ushort_t v = f2bfbits((acc[m][n][r] + bv_) * scale);
                if (sel == 0)      Qb[((size_t)bh * SEQ + s) * HEAD + d] = v;
                else if (sel == 1) Kb[((size_t)bh * SEQ + s) * HEAD + d] = v;
                else               Vt2[(((size_t)bh * 64 + (s >> 5)) * 32 + d) * 32 + (s & 31)] = v;
            }
        }
    }
}

// ---------------- Flash attention: swapped QK^T + intra-block split-K x4 ----
// Block = (b,h,qtile); wave w owns k-quarter w (16 tiles of 32).  All global
// loads are contiguous-1KB per instruction.  Mask is skipped per-tile via the
// prescan flags (gathered f32 fallback only for nonzero tiles).
__global__ __launch_bounds__(256, 8) void attn(
    const ushort_t* __restrict__ Qb, const ushort_t* __restrict__ Kb,
    const ushort_t* __restrict__ Vt2, const float* __restrict__ mask,
    const unsigned long long* __restrict__ flagsG, float* __restrict__ out)
{
    int g  = blockIdx.x;
    int qt = g >> 4;
    int b  = (g >> 3) & 1;
    int h  = g & 7;
    int bh = b * NHEAD + h;
    int w  = threadIdx.x >> 6;
    int l  = threadIdx.x & 63;
    int qs0 = qt * 16;
    int l15 = l & 15, lq = l >> 4;

    __shared__ ushort_t plds[4][16][40];     // P^T transpose tile per wave
    __shared__ float oacc[4][16][34];        // per-wave partial O
    __shared__ float om[4][16], ol[4][16];   // per-wave m, l stats
    ushort_t (*P)[40] = plds[w];

    bf16x8 qf = *reinterpret_cast<const bf16x8*>(
        Qb + ((size_t)bh * SEQ + qs0 + l15) * HEAD + lq * 8);

    unsigned long long fbits = flagsG[b * 128 + qt];

    f32x4 acc0 = {0.f, 0.f, 0.f, 0.f}, acc1 = {0.f, 0.f, 0.f, 0.f};
    float mrun = -1e30f, lsum = 0.f;   // stats for q=l15 (lsum lane-partial)

    int k0 = w * (SEQ / 4);
    int kb0 = k0 >> 5;                 // first V k-block for this wave
    const ushort_t* kbase = Kb + ((size_t)bh * SEQ + k0 + l15) * HEAD + lq * 8;
    const ushort_t* vbase = Vt2 + (size_t)bh * 64 * 32 * 32 + lq * 8;

    // prefetch tile 0
    bf16x8 kc0 = *(const bf16x8*)(kbase);
    bf16x8 kc1 = *(const bf16x8*)(kbase + 16 * HEAD);
    bf16x8 vc0 = *(const bf16x8*)(vbase + ((size_t)kb0 * 32 + l15) * 32);
    bf16x8 vc1 = *(const bf16x8*)(vbase + ((size_t)kb0 * 32 + 16 + l15) * 32);

    const int NT = (SEQ / 4) / 32;   // 16 tiles per wave
    #pragma unroll 2
    for (int kt = 0; kt < NT; kt++) {
        int ktn = (kt + 1 < NT) ? kt + 1 : 0;   // wrap: prefetch discarded
        f32x4 z = {0.f, 0.f, 0.f, 0.f};
        // S^T[k][q]: col=l15=q, rows lq*4+r = k (tile-local), +16 for kc1
        f32x4 s0 = __builtin_amdgcn_mfma_f32_16x16x32_bf16(kc0, qf, z, 0, 0, 0);
        f32x4 s1 = __builtin_amdgcn_mfma_f32_16x16x32_bf16(kc1, qf, z, 0, 0, 0);

        // prefetch next tile (overlaps softmax)
        bf16x8 kn0 = *(const bf16x8*)(kbase + (size_t)ktn * 32 * HEAD);
        bf16x8 kn1 = *(const bf16x8*)(kbase + (size_t)(ktn * 32 + 16) * HEAD);
        bf16x8 vn0 = *(const bf16x8*)(vbase + ((size_t)(kb0 + ktn) * 32 + l15) * 32);
        bf16x8 vn1 = *(const bf16x8*)(vbase + ((size_t)(kb0 + ktn) * 32 + 16 + l15) * 32);

        float sv[8];
        #pragma unroll
        for (int j = 0; j < 4; j++) { sv[j] = s0[j]; sv[4 + j] = s1[j]; }

        if ((fbits >> (w * 16 + kt)) & 1ull) {   // nonzero mask tile: rare path
            const float* mr = mask + (size_t)b * SEQ * SEQ
                            + (size_t)(qs0 + l15) * SEQ + k0 + kt * 32;
            float4 ma = *(const float4*)(mr + lq * 4);
            float4 mb = *(const float4*)(mr + 16 + lq * 4);
            sv[0] += ma.x; sv[1] += ma.y; sv[2] += ma.z; sv[3] += ma.w;
            sv[4] += mb.x; sv[5] += mb.y; sv[6] += mb.z; sv[7] += mb.w;
        }

        float lmax = fmaxf(fmaxf(fmaxf(sv[0], sv[1]), fmaxf(sv[2], sv[3])),
                           fmaxf(fmaxf(sv[4], sv[5]), fmaxf(sv[6], sv[7])));
        if (__any(lmax > mrun + 8.0f)) {   // defer-max rescale (rare)
            float pm = fmaxf(lmax, __shfl_xor(lmax, 16));
            pm = fmaxf(pm, __shfl_xor(pm, 32));
            float nm = fmaxf(mrun, pm);
            float sc = __expf(mrun - nm);
            lsum *= sc;
            #pragma unroll
            for (int r = 0; r < 4; r++) {
                float scr = __shfl(sc, (l & 48) | (lq * 4 + r));
                acc0[r] *= scr;
                acc1[r] *= scr;
            }
            mrun = nm;
        }

        float e[8];
        #pragma unroll
        for (int j = 0; j < 8; j++) e[j] = __expf(sv[j] - mrun);
        lsum += ((e[0] + e[1]) + (e[2] + e[3])) + ((e[4] + e[5]) + (e[6] + e[7]));

        // P[q=l15][k]: pairs packed by v_cvt_pk_bf16_f32, two b64 writes
        char* prow = (char*)&P[l15][0];
        *(uint2*)(prow + lq * 8)      = make_uint2(cvtpk(e[0], e[1]), cvtpk(e[2], e[3]));
        *(uint2*)(prow + 32 + lq * 8) = make_uint2(cvtpk(e[4], e[5]), cvtpk(e[6], e[7]));

        asm volatile("s_waitcnt lgkmcnt(0)" ::: "memory");
        __builtin_amdgcn_sched_barrier(0);

        bf16x8 pf = *reinterpret_cast<const bf16x8*>(&P[l15][lq * 8]);
        acc0 = __builtin_amdgcn_mfma_f32_16x16x32_bf16(pf, vc0, acc0, 0, 0, 0);
        acc1 = __builtin_amdgcn_mfma_f32_16x16x32_bf16(pf, vc1, acc1, 0, 0, 0);

        kc0 = kn0; kc1 = kn1; vc0 = vn0; vc1 = vn1;
    }

    // finalize lane-partial lsum across lq replicas
    lsum += __shfl_xor(lsum, 16);
    lsum += __shfl_xor(lsum, 32);

    // publish partials
    #pragma unroll
    for (int r = 0; r < 4; r++) {
        oacc[w][lq * 4 + r][l15]      = acc0[r];
        oacc[w][lq * 4 + r][16 + l15] = acc1[r];
    }
    if (lq == 0) { om[w][l15] = mrun; ol[w][l15] = lsum; }
    __syncthreads();

    // merge 4 k-quarters: 512 outputs, float4 per thread (threads 0..127)
    int t = threadIdx.x;
    if (t < 128) {
        int q = t >> 3, d4 = (t & 7) << 2;
        float m0 = om[0][q], m1 = om[1][q], m2 = om[2][q], m3 = om[3][q];
        float mg = fmaxf(fmaxf(m0, m1), fmaxf(m2, m3));
        float w0 = __expf(m0 - mg), w1 = __expf(m1 - mg);
        float w2 = __expf(m2 - mg), w3 = __expf(m3 - mg);
        float lg = w0 * ol[0][q] + w1 * ol[1][q] + w2 * ol[2][q] + w3 * ol[3][q];
        float inv = 1.0f / lg;
        float4 o;
        float* op = &o.x;
        #pragma unroll
        for (int j = 0; j < 4; j++) {
            int d = d4 + j;
            op[j] = (w0 * oacc[0][q][d] + w1 * oacc[1][q][d]
                   + w2 * oacc[2][q][d] + w3 * oacc[3][q][d]) * inv;
        }
        *(float4*)(out + ((size_t)(qs0 + q) * BATCH + b) * EMS + h * HEAD + d4) = o;
    }
}

extern "C" void kernel_launch(void* const* d_in, const int* in_sizes, int n_in,
                              void* d_out, int out_size, void* d_ws, size_t ws_size,
                              hipStream_t stream) {
    const float* em  = (const float*)d_in[0];
    const float* mask = (const float*)d_in[1];
    const float* Wq  = (const float*)d_in[2];
    const float* bq  = (const float*)d_in[3];
    const float* Wk  = (const float*)d_in[4];
    const float* bk  = (const float*)d_in[5];
    const float* Wv  = (const float*)d_in[6];
    const float* bv  = (const float*)d_in[7];
    float* out = (float*)d_out;

    ushort_t* Qb  = (ushort_t*)d_ws;                      // [BH][S][D] bf16, 2MB
    ushort_t* Kb  = Qb + (size_t)BH * SEQ * HEAD;         // 2MB
    ushort_t* Vt2 = Kb + (size_t)BH * SEQ * HEAD;         // [BH][64][32][32] bf16, 2MB
    unsigned* flagsG = (unsigned*)(Vt2 + (size_t)BH * SEQ * HEAD);  // 2KB

    fused_pre<<<dim3(1280), dim3(256), 0, stream>>>(em, mask, Wq, bq, Wk, bk, Wv, bv,
                                                    Qb, Kb, Vt2, flagsG);
    attn<<<dim3(2048), dim3(256), 0, stream>>>(Qb, Kb, Vt2, mask,
                                               (const unsigned long long*)flagsG, out);
}

// Round 5
// 72.874 us; speedup vs baseline: 1.9154x; 1.9154x over previous
//
#include <hip/hip_runtime.h>
#include <hip/hip_bf16.h>

typedef float f32x4 __attribute__((ext_vector_type(4)));
typedef __bf16 bf16x8 __attribute__((ext_vector_type(8)));
typedef unsigned short ushort_t;

#define SEQ 2048
#define BATCH 2
#define EMS 256
#define NHEAD 8
#define HEAD 32
#define BH (BATCH*NHEAD)

static __device__ __forceinline__ ushort_t f2bfbits(float f) {
    unsigned int u = __float_as_uint(f);
    u += 0x7fffu + ((u >> 16) & 1u);   // round-to-nearest-even
    return (ushort_t)(u >> 16);
}

static __device__ __forceinline__ unsigned cvtpk(float lo, float hi) {
    unsigned r;
    asm("v_cvt_pk_bf16_f32 %0, %1, %2" : "=v"(r) : "v"(lo), "v"(hi));
    return r;
}

static __device__ __forceinline__ bf16x8 cvt8(const float* p) {
    float4 a = *reinterpret_cast<const float4*>(p);
    float4 b = *reinterpret_cast<const float4*>(p + 4);
    union { bf16x8 v; uint4 u; } x;
    x.u.x = cvtpk(a.x, a.y);
    x.u.y = cvtpk(a.z, a.w);
    x.u.z = cvtpk(b.x, b.y);
    x.u.w = cvtpk(b.z, b.w);
    return x.v;
}

// ---------------- Fused pre-pass ----------------
// Blocks [0,512): mask nonzero-scan -> 64-bit flags per (b, qtile).
// Blocks [512,1280): QKV projection, 32x32 wave tiles.  V written in blocked-
// transposed layout Vt2[bh][kblk][32d][32kin] -> attn PV loads contiguous-1KB.
__global__ __launch_bounds__(256) void fused_pre(
    const float* __restrict__ em, const float* __restrict__ mask,
    const float* __restrict__ Wq, const float* __restrict__ bq,
    const float* __restrict__ Wk, const float* __restrict__ bk,
    const float* __restrict__ Wv, const float* __restrict__ bv,
    ushort_t* __restrict__ Qb, ushort_t* __restrict__ Kb,
    ushort_t* __restrict__ Vt2, unsigned* __restrict__ flagsG)
{
    if (blockIdx.x < 512) {
        // ---- mask scan: block = (b, qt, khalf) covers 16 rows x 1024 cols
        int fb = blockIdx.x;
        int kh = fb & 1, qt = (fb >> 1) & 127, b = fb >> 8;
        int t = threadIdx.x;
        const float* base = mask + ((size_t)b * SEQ + qt * 16) * SEQ + kh * 1024 + t * 4;
        unsigned nz = 0;
        #pragma unroll 4
        for (int it = 0; it < 16; it++) {
            float4 v = *(const float4*)(base + (size_t)it * SEQ);
            if (v.x != 0.f || v.y != 0.f || v.z != 0.f || v.w != 0.f) nz = 1;
        }
        __shared__ unsigned fl;
        if (t == 0) fl = 0;
        __syncthreads();
        if (nz) atomicOr(&fl, 1u << (t >> 3));   // 8 float4 per 32-wide k-tile
        __syncthreads();
        if (t == 0) flagsG[(b * 128 + qt) * 2 + kh] = fl;
        return;
    }

    // ---- QKV projection
    int wid = (blockIdx.x - 512) * 4 + (threadIdx.x >> 6);
    int l   = threadIdx.x & 63;
    int l15 = l & 15, lq = l >> 4;
    int rb = wid / 24, cg = wid % 24;
    int r0 = rb * 32, c0 = cg * 32;
    int sel = c0 >> 8;                       // 0=Q 1=K 2=V (uniform per wave)
    const float* W    = sel == 0 ? Wq : (sel == 1 ? Wk : Wv);
    const float* bias = sel == 0 ? bq : (sel == 1 ? bk : bv);
    int cb = c0 & 255;

    f32x4 acc[2][2];
    #pragma unroll
    for (int m = 0; m < 2; m++)
        #pragma unroll
        for (int n = 0; n < 2; n++) acc[m][n] = (f32x4){0.f, 0.f, 0.f, 0.f};

    #pragma unroll
    for (int kk = 0; kk < 8; kk++) {
        int k0 = kk * 32;
        bf16x8 af[2], bfm[2];
        #pragma unroll
        for (int m = 0; m < 2; m++)
            af[m] = cvt8(em + (size_t)(r0 + m * 16 + l15) * EMS + k0 + lq * 8);
        #pragma unroll
        for (int n = 0; n < 2; n++)
            bfm[n] = cvt8(W + (size_t)(cb + n * 16 + l15) * EMS + k0 + lq * 8);
        #pragma unroll
        for (int m = 0; m < 2; m++)
            #pragma unroll
            for (int n = 0; n < 2; n++)
                acc[m][n] = __builtin_amdgcn_mfma_f32_16x16x32_bf16(af[m], bfm[n], acc[m][n], 0, 0, 0);
    }

    float scale = (sel == 0) ? 0.17677669529663687f : 1.0f;  // 1/sqrt(32) in Q
    #pragma unroll
    for (int m = 0; m < 2; m++) {
        #pragma unroll
        for (int n = 0; n < 2; n++) {
            int c = cb + n * 16 + l15;
            float bv_ = bias[c];
            int h = c >> 5, d = c & 31;
            #pragma unroll
            for (int r = 0; r < 4; r++) {
                int row = r0 + m * 16 + lq * 4 + r;   // C/D: row=(l>>4)*4+reg, col=l&15
                int s = row >> 1, b = row & 1;
                int bh = b * NHEAD + h;
                ushort_t v = f2bfbits((acc[m][n][r] + bv_) * scale);
                if (sel == 0)      Qb[((size_t)bh * SEQ + s) * HEAD + d] = v;
                else if (sel == 1) Kb[((size_t)bh * SEQ + s) * HEAD + d] = v;
                else               Vt2[(((size_t)bh * 64 + (s >> 5)) * 32 + d) * 32 + (s & 31)] = v;
            }
        }
    }
}

// ---------------- Flash attention: swapped QK^T + intra-block split-K x4 ----
// Block = (b,h,qtile); wave w owns k-quarter w (16 tiles of 32).  All global
// loads contiguous-1KB/instr.  Mask skipped per-tile via prescan flags.
// NOTE: min-waves = 4 (not 8!) -- 8 capped VGPRs at 32 and spilled the whole
// pipeline to scratch (R4: WRITE_SIZE 280MB).  Working set ~100 VGPR.
__global__ __launch_bounds__(256, 4) void attn(
    const ushort_t* __restrict__ Qb, const ushort_t* __restrict__ Kb,
    const ushort_t* __restrict__ Vt2, const float* __restrict__ mask,
    const unsigned long long* __restrict__ flagsG, float* __restrict__ out)
{
    int g  = blockIdx.x;
    int qt = g >> 4;
    int b  = (g >> 3) & 1;
    int h  = g & 7;
    int bh = b * NHEAD + h;
    int w  = threadIdx.x >> 6;
    int l  = threadIdx.x & 63;
    int qs0 = qt * 16;
    int l15 = l & 15, lq = l >> 4;

    __shared__ ushort_t plds[4][16][40];     // P^T transpose tile per wave
    __shared__ float oacc[4][16][34];        // per-wave partial O
    __shared__ float om[4][16], ol[4][16];   // per-wave m, l stats
    ushort_t (*P)[40] = plds[w];

    bf16x8 qf = *reinterpret_cast<const bf16x8*>(
        Qb + ((size_t)bh * SEQ + qs0 + l15) * HEAD + lq * 8);

    unsigned long long fbits = flagsG[b * 128 + qt];

    f32x4 acc0 = {0.f, 0.f, 0.f, 0.f}, acc1 = {0.f, 0.f, 0.f, 0.f};
    float mrun = -1e30f, lsum = 0.f;   // stats for q=l15 (lsum lane-partial)

    int k0 = w * (SEQ / 4);
    int kb0 = k0 >> 5;                 // first V k-block for this wave
    const ushort_t* kbase = Kb + ((size_t)bh * SEQ + k0 + l15) * HEAD + lq * 8;
    const ushort_t* vbase = Vt2 + (size_t)bh * 64 * 32 * 32 + lq * 8;

    // prefetch tile 0
    bf16x8 kc0 = *(const bf16x8*)(kbase);
    bf16x8 kc1 = *(const bf16x8*)(kbase + 16 * HEAD);
    bf16x8 vc0 = *(const bf16x8*)(vbase + ((size_t)kb0 * 32 + l15) * 32);
    bf16x8 vc1 = *(const bf16x8*)(vbase + ((size_t)kb0 * 32 + 16 + l15) * 32);

    const int NT = (SEQ / 4) / 32;   // 16 tiles per wave
    #pragma unroll 2
    for (int kt = 0; kt < NT; kt++) {
        int ktn = (kt + 1 < NT) ? kt + 1 : 0;   // wrap: prefetch discarded
        f32x4 z = {0.f, 0.f, 0.f, 0.f};
        // S^T[k][q]: col=l15=q, rows lq*4+r = k (tile-local), +16 for kc1
        f32x4 s0 = __builtin_amdgcn_mfma_f32_16x16x32_bf16(kc0, qf, z, 0, 0, 0);
        f32x4 s1 = __builtin_amdgcn_mfma_f32_16x16x32_bf16(kc1, qf, z, 0, 0, 0);

        // prefetch next tile (overlaps softmax)
        bf16x8 kn0 = *(const bf16x8*)(kbase + (size_t)ktn * 32 * HEAD);
        bf16x8 kn1 = *(const bf16x8*)(kbase + (size_t)(ktn * 32 + 16) * HEAD);
        bf16x8 vn0 = *(const bf16x8*)(vbase + ((size_t)(kb0 + ktn) * 32 + l15) * 32);
        bf16x8 vn1 = *(const bf16x8*)(vbase + ((size_t)(kb0 + ktn) * 32 + 16 + l15) * 32);

        float sv[8];
        #pragma unroll
        for (int j = 0; j < 4; j++) { sv[j] = s0[j]; sv[4 + j] = s1[j]; }

        if ((fbits >> (w * 16 + kt)) & 1ull) {   // nonzero mask tile: rare path
            const float* mr = mask + (size_t)b * SEQ * SEQ
                            + (size_t)(qs0 + l15) * SEQ + k0 + kt * 32;
            float4 ma = *(const float4*)(mr + lq * 4);
            float4 mb = *(const float4*)(mr + 16 + lq * 4);
            sv[0] += ma.x; sv[1] += ma.y; sv[2] += ma.z; sv[3] += ma.w;
            sv[4] += mb.x; sv[5] += mb.y; sv[6] += mb.z; sv[7] += mb.w;
        }

        float lmax = fmaxf(fmaxf(fmaxf(sv[0], sv[1]), fmaxf(sv[2], sv[3])),
                           fmaxf(fmaxf(sv[4], sv[5]), fmaxf(sv[6], sv[7])));
        if (__any(lmax > mrun + 8.0f)) {   // defer-max rescale (rare)
            float pm = fmaxf(lmax, __shfl_xor(lmax, 16));
            pm = fmaxf(pm, __shfl_xor(pm, 32));
            float nm = fmaxf(mrun, pm);
            float sc = __expf(mrun - nm);
            lsum *= sc;
            #pragma unroll
            for (int r = 0; r < 4; r++) {
                float scr = __shfl(sc, (l & 48) | (lq * 4 + r));
                acc0[r] *= scr;
                acc1[r] *= scr;
            }
            mrun = nm;
        }

        float e[8];
        #pragma unroll
        for (int j = 0; j < 8; j++) e[j] = __expf(sv[j] - mrun);
        lsum += ((e[0] + e[1]) + (e[2] + e[3])) + ((e[4] + e[5]) + (e[6] + e[7]));

        // P[q=l15][k]: pairs packed by v_cvt_pk_bf16_f32, two b64 writes
        char* prow = (char*)&P[l15][0];
        *(uint2*)(prow + lq * 8)      = make_uint2(cvtpk(e[0], e[1]), cvtpk(e[2], e[3]));
        *(uint2*)(prow + 32 + lq * 8) = make_uint2(cvtpk(e[4], e[5]), cvtpk(e[6], e[7]));

        asm volatile("s_waitcnt lgkmcnt(0)" ::: "memory");
        __builtin_amdgcn_sched_barrier(0);

        bf16x8 pf = *reinterpret_cast<const bf16x8*>(&P[l15][lq * 8]);
        acc0 = __builtin_amdgcn_mfma_f32_16x16x32_bf16(pf, vc0, acc0, 0, 0, 0);
        acc1 = __builtin_amdgcn_mfma_f32_16x16x32_bf16(pf, vc1, acc1, 0, 0, 0);

        kc0 = kn0; kc1 = kn1; vc0 = vn0; vc1 = vn1;
    }

    // finalize lane-partial lsum across lq replicas
    lsum += __shfl_xor(lsum, 16);
    lsum += __shfl_xor(lsum, 32);

    // publish partials
    #pragma unroll
    for (int r = 0; r < 4; r++) {
        oacc[w][lq * 4 + r][l15]      = acc0[r];
        oacc[w][lq * 4 + r][16 + l15] = acc1[r];
    }
    if (lq == 0) { om[w][l15] = mrun; ol[w][l15] = lsum; }
    __syncthreads();

    // merge 4 k-quarters: 512 outputs, float4 per thread (threads 0..127)
    int t = threadIdx.x;
    if (t < 128) {
        int q = t >> 3, d4 = (t & 7) << 2;
        float m0 = om[0][q], m1 = om[1][q], m2 = om[2][q], m3 = om[3][q];
        float mg = fmaxf(fmaxf(m0, m1), fmaxf(m2, m3));
        float w0 = __expf(m0 - mg), w1 = __expf(m1 - mg);
        float w2 = __expf(m2 - mg), w3 = __expf(m3 - mg);
        float lg = w0 * ol[0][q] + w1 * ol[1][q] + w2 * ol[2][q] + w3 * ol[3][q];
        float inv = 1.0f / lg;
        float4 o;
        float* op = &o.x;
        #pragma unroll
        for (int j = 0; j < 4; j++) {
            int d = d4 + j;
            op[j] = (w0 * oacc[0][q][d] + w1 * oacc[1][q][d]
                   + w2 * oacc[2][q][d] + w3 * oacc[3][q][d]) * inv;
        }
        *(float4*)(out + ((size_t)(qs0 + q) * BATCH + b) * EMS + h * HEAD + d4) = o;
    }
}

extern "C" void kernel_launch(void* const* d_in, const int* in_sizes, int n_in,
                              void* d_out, int out_size, void* d_ws, size_t ws_size,
                              hipStream_t stream) {
    const float* em  = (const float*)d_in[0];
    const float* mask = (const float*)d_in[1];
    const float* Wq  = (const float*)d_in[2];
    const float* bq  = (const float*)d_in[3];
    const float* Wk  = (const float*)d_in[4];
    const float* bk  = (const float*)d_in[5];
    const float* Wv  = (const float*)d_in[6];
    const float* bv  = (const float*)d_in[7];
    float* out = (float*)d_out;

    ushort_t* Qb  = (ushort_t*)d_ws;                      // [BH][S][D] bf16, 2MB
    ushort_t* Kb  = Qb + (size_t)BH * SEQ * HEAD;         // 2MB
    ushort_t* Vt2 = Kb + (size_t)BH * SEQ * HEAD;         // [BH][64][32][32] bf16, 2MB
    unsigned* flagsG = (unsigned*)(Vt2 + (size_t)BH * SEQ * HEAD);  // 2KB

    fused_pre<<<dim3(1280), dim3(256), 0, stream>>>(em, mask, Wq, bq, Wk, bk, Wv, bv,
                                                    Qb, Kb, Vt2, flagsG);
    attn<<<dim3(2048), dim3(256), 0, stream>>>(Qb, Kb, Vt2, mask,
                                               (const unsigned long long*)flagsG, out);
}

// Round 7
// 54.177 us; speedup vs baseline: 2.5764x; 1.3451x over previous
//
#include <hip/hip_runtime.h>
#include <hip/hip_bf16.h>

typedef float f32x4 __attribute__((ext_vector_type(4)));
typedef float f32x16 __attribute__((ext_vector_type(16)));
typedef __bf16 bf16x8 __attribute__((ext_vector_type(8)));
typedef int v2i __attribute__((ext_vector_type(2)));
typedef unsigned short ushort_t;

#define SEQ 2048
#define BATCH 2
#define EMS 256
#define NHEAD 8
#define HEAD 32
#define BH (BATCH*NHEAD)
#define LOG2E 1.4426950408889634f
#define QSCALE 0.2550348211f      /* log2(e)/sqrt(32) */
#define THRS 11.5415603f          /* 8*log2(e): defer-max bound e^8 */

static __device__ __forceinline__ ushort_t f2bfbits(float f) {
    unsigned int u = __float_as_uint(f);
    u += 0x7fffu + ((u >> 16) & 1u);
    return (ushort_t)(u >> 16);
}

static __device__ __forceinline__ unsigned cvtpk(float lo, float hi) {
    unsigned r;
    asm("v_cvt_pk_bf16_f32 %0, %1, %2" : "=v"(r) : "v"(lo), "v"(hi));
    return r;
}

static __device__ __forceinline__ float exp2a(float x) {
    float r;
    asm("v_exp_f32 %0, %1" : "=v"(r) : "v"(x));
    return r;
}

static __device__ __forceinline__ bf16x8 cvt8(const float* p) {
    float4 a = *reinterpret_cast<const float4*>(p);
    float4 b = *reinterpret_cast<const float4*>(p + 4);
    union { bf16x8 v; uint4 u; } x;
    x.u.x = cvtpk(a.x, a.y);
    x.u.y = cvtpk(a.z, a.w);
    x.u.z = cvtpk(b.x, b.y);
    x.u.w = cvtpk(b.z, b.w);
    return x.v;
}

// ---------------- Fused pre-pass ----------------
// Blocks [0,1024): mask nonzero-scan, fully coalesced.  Decomposition uses
// exactly 10 bits: kq(2) + qt(7) + b(1) -> 1024 blocks.  (R6 crash: launched
// 2048 -> b=2,3 read 33MB past mask.)
// Blocks [1024,1792): QKV projection.  Q pre-scaled by log2(e)/sqrt(32).
__global__ __launch_bounds__(256) void fused_pre(
    const float* __restrict__ em, const float* __restrict__ mask,
    const float* __restrict__ Wq, const float* __restrict__ bq,
    const float* __restrict__ Wk, const float* __restrict__ bk,
    const float* __restrict__ Wv, const float* __restrict__ bv,
    ushort_t* __restrict__ Qb, ushort_t* __restrict__ Kb,
    ushort_t* __restrict__ Vt2, unsigned long long* __restrict__ flagsG)
{
    if (blockIdx.x < 1024) {
        // block = (b, qt16, kq): 16 q-rows x 512 k-cols
        int fb = blockIdx.x;
        int kq = fb & 3, qt = (fb >> 2) & 127, b = fb >> 9;   // fb<1024 -> b in {0,1}
        int t = threadIdx.x;
        int r = t >> 4, i = t & 15;
        const float* base = mask + ((size_t)b * SEQ + qt * 16 + r) * SEQ + kq * 512 + i * 4;
        unsigned nzb = 0;
        #pragma unroll
        for (int j = 0; j < 8; j++) {
            float4 v = *(const float4*)(base + j * 64);
            unsigned u = (__float_as_uint(v.x) | __float_as_uint(v.y) |
                          __float_as_uint(v.z) | __float_as_uint(v.w)) << 1;  // <<1 kills ±0
            if (u) nzb |= 1u << (2 * j + (i >> 3));   // local 32-col tile id
        }
        __shared__ unsigned fl;
        if (t == 0) fl = 0;
        __syncthreads();
        if (nzb) atomicOr(&fl, nzb);
        __syncthreads();
        if (t == 0) ((ushort_t*)flagsG)[(b * 128 + qt) * 4 + kq] = (ushort_t)fl;
        return;
    }

    // ---- QKV projection (32x32 wave tiles)
    int wid = (blockIdx.x - 1024) * 4 + (threadIdx.x >> 6);
    int l   = threadIdx.x & 63;
    int l15 = l & 15, lq = l >> 4;
    int rb = wid / 24, cg = wid % 24;
    int r0 = rb * 32, c0 = cg * 32;
    int sel = c0 >> 8;                       // 0=Q 1=K 2=V (uniform per wave)
    const float* W    = sel == 0 ? Wq : (sel == 1 ? Wk : Wv);
    const float* bias = sel == 0 ? bq : (sel == 1 ? bk : bv);
    int cb = c0 & 255;

    f32x4 acc[2][2];
    #pragma unroll
    for (int m = 0; m < 2; m++)
        #pragma unroll
        for (int n = 0; n < 2; n++) acc[m][n] = (f32x4){0.f, 0.f, 0.f, 0.f};

    #pragma unroll
    for (int kk = 0; kk < 8; kk++) {
        int k0 = kk * 32;
        bf16x8 af[2], bfm[2];
        #pragma unroll
        for (int m = 0; m < 2; m++)
            af[m] = cvt8(em + (size_t)(r0 + m * 16 + l15) * EMS + k0 + lq * 8);
        #pragma unroll
        for (int n = 0; n < 2; n++)
            bfm[n] = cvt8(W + (size_t)(cb + n * 16 + l15) * EMS + k0 + lq * 8);
        #pragma unroll
        for (int m = 0; m < 2; m++)
            #pragma unroll
            for (int n = 0; n < 2; n++)
                acc[m][n] = __builtin_amdgcn_mfma_f32_16x16x32_bf16(af[m], bfm[n], acc[m][n], 0, 0, 0);
    }

    float scale = (sel == 0) ? QSCALE : 1.0f;   // log2e/sqrt(D) folded into Q
    #pragma unroll
    for (int m = 0; m < 2; m++) {
        #pragma unroll
        for (int n = 0; n < 2; n++) {
            int c = cb + n * 16 + l15;
            float bv_ = bias[c];
            int h = c >> 5, d = c & 31;
            #pragma unroll
            for (int r = 0; r < 4; r++) {
                int row = r0 + m * 16 + lq * 4 + r;   // C/D: row=(l>>4)*4+reg, col=l&15
                int s = row >> 1, b = row & 1;
                int bh = b * NHEAD + h;
                ushort_t v = f2bfbits((acc[m][n][r] + bv_) * scale);
                if (sel == 0)      Qb[((size_t)bh * SEQ + s) * HEAD + d] = v;
                else if (sel == 1) Kb[((size_t)bh * SEQ + s) * HEAD + d] = v;
                else               Vt2[(((size_t)bh * 64 + (s >> 5)) * 32 + d) * 32 + (s & 31)] = v;
            }
        }
    }
}

// ---------------- Flash attention: 32x32 MFMA, zero-LDS main loop ----------
// Block = (b,h,32-row qtile); wave w owns k-quarter w (16 tiles of 32).
// S^T = mfma(K,Q) 32x32: lane owns q=l&31, 16 scores in regs (k = (reg&3)+
// 8*(reg>>2)+4*hi).  Softmax in-lane; P->bf16 via cvt_pk + permlane32_swap
// (no LDS / no waitcnt on the chain).  PV: O^T = mfma(V^T, P^T).
__global__ __launch_bounds__(256, 4) void attn(
    const ushort_t* __restrict__ Qb, const ushort_t* __restrict__ Kb,
    const ushort_t* __restrict__ Vt2, const float* __restrict__ mask,
    const unsigned long long* __restrict__ flagsG, float* __restrict__ out)
{
    int g  = blockIdx.x;
    int qt = g >> 4;              // 0..63 (32-row tiles)
    int b  = (g >> 3) & 1;
    int h  = g & 7;
    int bh = b * NHEAD + h;
    int w  = threadIdx.x >> 6;
    int l  = threadIdx.x & 63;
    int l31 = l & 31, hi = l >> 5;
    int qs0 = qt * 32;

    __shared__ float oacc[4][32][36];
    __shared__ float om[4][32], ol[4][32];

    const ushort_t* qrow = Qb + ((size_t)bh * SEQ + qs0 + l31) * HEAD + hi * 8;
    bf16x8 qf0 = *(const bf16x8*)(qrow);        // d 0..15 fragment
    bf16x8 qf1 = *(const bf16x8*)(qrow + 16);   // d 16..31

    unsigned long long fbits = flagsG[b * 128 + qt * 2] | flagsG[b * 128 + qt * 2 + 1];

    f32x16 acc = {};
    float mrun = -1e30f, lsum = 0.f;            // per-lane, q = l31

    int k0 = w * (SEQ / 4);
    const ushort_t* kbase = Kb  + ((size_t)bh * SEQ + k0 + l31) * HEAD + hi * 8;
    const ushort_t* vbase = Vt2 + ((size_t)bh * 64 + (k0 >> 5)) * 1024 + l31 * 32 + hi * 8;

    bf16x8 kc0 = *(const bf16x8*)(kbase);
    bf16x8 kc1 = *(const bf16x8*)(kbase + 16);
    bf16x8 vc0 = *(const bf16x8*)(vbase);
    bf16x8 vc1 = *(const bf16x8*)(vbase + 16);

    const int NT = (SEQ / 4) / 32;   // 16 tiles per wave
    for (int kt = 0; kt < NT; kt++) {
        int ktn = (kt + 1 < NT) ? kt + 1 : 0;   // wrap: prefetch discarded
        f32x16 st = {};
        st = __builtin_amdgcn_mfma_f32_32x32x16_bf16(kc0, qf0, st, 0, 0, 0);
        st = __builtin_amdgcn_mfma_f32_32x32x16_bf16(kc1, qf1, st, 0, 0, 0);

        bf16x8 kn0 = *(const bf16x8*)(kbase + ktn * 1024);
        bf16x8 kn1 = *(const bf16x8*)(kbase + ktn * 1024 + 16);
        bf16x8 vn0 = *(const bf16x8*)(vbase + ktn * 1024);
        bf16x8 vn1 = *(const bf16x8*)(vbase + ktn * 1024 + 16);

        if ((fbits >> (w * 16 + kt)) & 1ull) {   // nonzero mask tile: rare path
            const float* mr = mask + (size_t)b * SEQ * SEQ
                            + (size_t)(qs0 + l31) * SEQ + k0 + kt * 32 + hi * 4;
            union { float4 f4[4]; float f[16]; } mu;
            mu.f4[0] = *(const float4*)(mr);
            mu.f4[1] = *(const float4*)(mr + 8);
            mu.f4[2] = *(const float4*)(mr + 16);
            mu.f4[3] = *(const float4*)(mr + 24);
            #pragma unroll
            for (int j = 0; j < 16; j++) st[j] += mu.f[j] * LOG2E;
        }

        float x0 = fmaxf(st[0], st[1]),  x1 = fmaxf(st[2], st[3]);
        float x2 = fmaxf(st[4], st[5]),  x3 = fmaxf(st[6], st[7]);
        float x4 = fmaxf(st[8], st[9]),  x5 = fmaxf(st[10], st[11]);
        float x6 = fmaxf(st[12], st[13]), x7 = fmaxf(st[14], st[15]);
        float lmax = fmaxf(fmaxf(fmaxf(x0, x1), fmaxf(x2, x3)),
                           fmaxf(fmaxf(x4, x5), fmaxf(x6, x7)));

        if (__any(lmax > mrun + THRS)) {   // defer-max rescale (rare)
            // both swap outputs together always contain {own, partner}
            v2i sw = __builtin_amdgcn_permlane32_swap(
                __float_as_int(lmax), __float_as_int(lmax), false, false);
            float pm = fmaxf(fmaxf(lmax, __int_as_float(sw.x)), __int_as_float(sw.y));
            float nm = fmaxf(mrun, pm);
            float sc = exp2a(mrun - nm);
            lsum *= sc;
            #pragma unroll
            for (int j = 0; j < 16; j++) acc[j] *= sc;   // q = own lane: no shuffle
            mrun = nm;
        }

        float ev[16];
        #pragma unroll
        for (int j = 0; j < 16; j++) ev[j] = exp2a(st[j] - mrun);
        lsum += (((ev[0]+ev[1])+(ev[2]+ev[3])) + ((ev[4]+ev[5])+(ev[6]+ev[7])))
              + (((ev[8]+ev[9])+(ev[10]+ev[11])) + ((ev[12]+ev[13])+(ev[14]+ev[15])));

        unsigned pk[8];
        #pragma unroll
        for (int j = 0; j < 8; j++) pk[j] = cvtpk(ev[2 * j], ev[2 * j + 1]);
        // P^T B-operand repack via permlane32_swap:
        //   new_a[l] = l<32 ? a[l] : b[l-32];  new_b[l] = l<32 ? a[l+32] : b[l]
        // pf0 = {p0.x,p1.x,p0.y,p1.y} -> k = hi*8 + 0..7; pf1 -> 16 + hi*8 + 0..7.
        v2i p0 = __builtin_amdgcn_permlane32_swap((int)pk[0], (int)pk[2], false, false);
        v2i p1 = __builtin_amdgcn_permlane32_swap((int)pk[1], (int)pk[3], false, false);
        v2i p2 = __builtin_amdgcn_permlane32_swap((int)pk[4], (int)pk[6], false, false);
        v2i p3 = __builtin_amdgcn_permlane32_swap((int)pk[5], (int)pk[7], false, false);
        union { int i[4]; bf16x8 v; } pf0, pf1;
        pf0.i[0] = p0.x; pf0.i[1] = p1.x; pf0.i[2] = p0.y; pf0.i[3] = p1.y;
        pf1.i[0] = p2.x; pf1.i[1] = p3.x; pf1.i[2] = p2.y; pf1.i[3] = p3.y;

        acc = __builtin_amdgcn_mfma_f32_32x32x16_bf16(vc0, pf0.v, acc, 0, 0, 0);
        acc = __builtin_amdgcn_mfma_f32_32x32x16_bf16(vc1, pf1.v, acc, 0, 0, 0);

        kc0 = kn0; kc1 = kn1; vc0 = vn0; vc1 = vn1;
    }

    // lsum across the two half-lanes of each q
    v2i sl = __builtin_amdgcn_permlane32_swap(
        __float_as_int(lsum), __float_as_int(lsum), false, false);
    float lt = __int_as_float(sl.x) + __int_as_float(sl.y);
    if (hi == 0) { om[w][l31] = mrun; ol[w][l31] = lt; }

    #pragma unroll
    for (int gg = 0; gg < 4; gg++) {    // acc reg 4g+j -> d = j + 8g + 4hi
        f32x4 vv = { acc[4*gg], acc[4*gg+1], acc[4*gg+2], acc[4*gg+3] };
        *(f32x4*)&oacc[w][l31][8 * gg + 4 * hi] = vv;
    }
    __syncthreads();

    // merge 4 k-quarters: 1024 outputs, one float4 per thread
    int t = threadIdx.x;
    int q = t >> 3, d4 = (t & 7) * 4;
    float m0 = om[0][q], m1 = om[1][q], m2 = om[2][q], m3 = om[3][q];
    float mg = fmaxf(fmaxf(m0, m1), fmaxf(m2, m3));
    float w0_ = exp2a(m0 - mg), w1_ = exp2a(m1 - mg);
    float w2_ = exp2a(m2 - mg), w3_ = exp2a(m3 - mg);
    float lg = w0_ * ol[0][q] + w1_ * ol[1][q] + w2_ * ol[2][q] + w3_ * ol[3][q];
    float inv = 1.0f / lg;
    float4 o;
    o.x = (w0_*oacc[0][q][d4]   + w1_*oacc[1][q][d4]   + w2_*oacc[2][q][d4]   + w3_*oacc[3][q][d4])   * inv;
    o.y = (w0_*oacc[0][q][d4+1] + w1_*oacc[1][q][d4+1] + w2_*oacc[2][q][d4+1] + w3_*oacc[3][q][d4+1]) * inv;
    o.z = (w0_*oacc[0][q][d4+2] + w1_*oacc[1][q][d4+2] + w2_*oacc[2][q][d4+2] + w3_*oacc[3][q][d4+2]) * inv;
    o.w = (w0_*oacc[0][q][d4+3] + w1_*oacc[1][q][d4+3] + w2_*oacc[2][q][d4+3] + w3_*oacc[3][q][d4+3]) * inv;
    *(float4*)(out + ((size_t)(qs0 + q) * BATCH + b) * EMS + h * HEAD + d4) = o;
}

extern "C" void kernel_launch(void* const* d_in, const int* in_sizes, int n_in,
                              void* d_out, int out_size, void* d_ws, size_t ws_size,
                              hipStream_t stream) {
    const float* em  = (const float*)d_in[0];
    const float* mask = (const float*)d_in[1];
    const float* Wq  = (const float*)d_in[2];
    const float* bq  = (const float*)d_in[3];
    const float* Wk  = (const float*)d_in[4];
    const float* bk  = (const float*)d_in[5];
    const float* Wv  = (const float*)d_in[6];
    const float* bv  = (const float*)d_in[7];
    float* out = (float*)d_out;

    ushort_t* Qb  = (ushort_t*)d_ws;                      // [BH][S][D] bf16, 2MB
    ushort_t* Kb  = Qb + (size_t)BH * SEQ * HEAD;         // 2MB
    ushort_t* Vt2 = Kb + (size_t)BH * SEQ * HEAD;         // [BH][64][32d][32k] bf16, 2MB
    unsigned long long* flagsG = (unsigned long long*)(Vt2 + (size_t)BH * SEQ * HEAD);  // 2KB

    fused_pre<<<dim3(1792), dim3(256), 0, stream>>>(em, mask, Wq, bq, Wk, bk, Wv, bv,
                                                    Qb, Kb, Vt2, flagsG);
    attn<<<dim3(1024), dim3(256), 0, stream>>>(Qb, Kb, Vt2, mask, flagsG, out);
}

// Round 8
// 51.707 us; speedup vs baseline: 2.6995x; 1.0478x over previous
//
#include <hip/hip_runtime.h>
#include <hip/hip_bf16.h>

typedef float f32x4 __attribute__((ext_vector_type(4)));
typedef float f32x16 __attribute__((ext_vector_type(16)));
typedef __bf16 bf16x8 __attribute__((ext_vector_type(8)));
typedef int v2i __attribute__((ext_vector_type(2)));
typedef unsigned short ushort_t;

#define SEQ 2048
#define BATCH 2
#define EMS 256
#define NHEAD 8
#define HEAD 32
#define BH (BATCH*NHEAD)
#define LOG2E 1.4426950408889634f
#define QSCALE 0.2550348211f      /* log2(e)/sqrt(32) */
#define THRS 11.5415603f          /* 8*log2(e): defer-max bound e^8 */

static __device__ __forceinline__ ushort_t f2bfbits(float f) {
    unsigned int u = __float_as_uint(f);
    u += 0x7fffu + ((u >> 16) & 1u);
    return (ushort_t)(u >> 16);
}

static __device__ __forceinline__ unsigned cvtpk(float lo, float hi) {
    unsigned r;
    asm("v_cvt_pk_bf16_f32 %0, %1, %2" : "=v"(r) : "v"(lo), "v"(hi));
    return r;
}

static __device__ __forceinline__ float exp2a(float x) {
    float r;
    asm("v_exp_f32 %0, %1" : "=v"(r) : "v"(x));
    return r;
}

static __device__ __forceinline__ bf16x8 cvt8(const float* p) {
    float4 a = *reinterpret_cast<const float4*>(p);
    float4 b = *reinterpret_cast<const float4*>(p + 4);
    union { bf16x8 v; uint4 u; } x;
    x.u.x = cvtpk(a.x, a.y);
    x.u.y = cvtpk(a.z, a.w);
    x.u.z = cvtpk(b.x, b.y);
    x.u.w = cvtpk(b.z, b.w);
    return x.v;
}

// ---------------- Fused pre-pass ----------------
// Blocks [0,384): QKV projection (R1 geometry: 32x64 wave tiles) -- dispatched
// FIRST so the latency-bound GEMM overlaps the BW-bound scan behind it.
// Blocks [384,896): mask nonzero-scan, 1KB-contiguous per wave-instruction
// (R7's 4x256B-segment pattern was a line-gather -> 888 GB/s; this streams).
__global__ __launch_bounds__(256) void fused_pre(
    const float* __restrict__ em, const float* __restrict__ mask,
    const float* __restrict__ Wq, const float* __restrict__ bq,
    const float* __restrict__ Wk, const float* __restrict__ bk,
    const float* __restrict__ Wv, const float* __restrict__ bv,
    ushort_t* __restrict__ Qb, ushort_t* __restrict__ Kb,
    ushort_t* __restrict__ Vb, unsigned* __restrict__ flagsG)
{
    if (blockIdx.x >= 384) {
        // ---- mask scan: block = (b, qt16, khalf): 16 rows x 1024 cols
        int sb = blockIdx.x - 384;
        int kh = sb & 1, qt = (sb >> 1) & 127, b = sb >> 8;   // sb<512 -> b in {0,1}
        int t = threadIdx.x;
        const float* base = mask + ((size_t)b * SEQ + qt * 16) * SEQ + kh * 1024 + t * 4;
        unsigned nz = 0;
        #pragma unroll 4
        for (int it = 0; it < 16; it++) {
            float4 v = *(const float4*)(base + (size_t)it * SEQ);
            unsigned u = (__float_as_uint(v.x) | __float_as_uint(v.y) |
                          __float_as_uint(v.z) | __float_as_uint(v.w)) << 1;  // <<1 kills ±0
            if (u) nz = 1;
        }
        __shared__ unsigned fl;
        if (t == 0) fl = 0;
        __syncthreads();
        if (nz) atomicOr(&fl, 1u << (t >> 3));    // 8 threads per 32-col k-tile
        __syncthreads();
        if (t == 0) flagsG[(b * 128 + qt) * 2 + kh] = fl;
        return;
    }

    // ---- QKV projection: wave = 32 rows x 64 cols of [Q|K|V] (768 cols)
    int wid = blockIdx.x * 4 + (threadIdx.x >> 6);   // < 1536
    int l   = threadIdx.x & 63;
    int l15 = l & 15, lq = l >> 4;
    int rb = wid / 12, cg = wid % 12;
    int r0 = rb * 32, c0 = cg * 64;
    int sel = c0 >> 8;                       // 0=Q 1=K 2=V (uniform per wave)
    const float* W    = sel == 0 ? Wq : (sel == 1 ? Wk : Wv);
    const float* bias = sel == 0 ? bq : (sel == 1 ? bk : bv);
    ushort_t*    dst  = sel == 0 ? Qb : (sel == 1 ? Kb : Vb);
    int cb = c0 & 255;

    f32x4 acc[2][4];
    #pragma unroll
    for (int m = 0; m < 2; m++)
        #pragma unroll
        for (int n = 0; n < 4; n++) acc[m][n] = (f32x4){0.f, 0.f, 0.f, 0.f};

    #pragma unroll
    for (int kk = 0; kk < 8; kk++) {
        int k0 = kk * 32;
        bf16x8 af[2], bfm[4];
        #pragma unroll
        for (int m = 0; m < 2; m++)
            af[m] = cvt8(em + (size_t)(r0 + m * 16 + l15) * EMS + k0 + lq * 8);
        #pragma unroll
        for (int n = 0; n < 4; n++)
            bfm[n] = cvt8(W + (size_t)(cb + n * 16 + l15) * EMS + k0 + lq * 8);
        #pragma unroll
        for (int m = 0; m < 2; m++)
            #pragma unroll
            for (int n = 0; n < 4; n++)
                acc[m][n] = __builtin_amdgcn_mfma_f32_16x16x32_bf16(af[m], bfm[n], acc[m][n], 0, 0, 0);
    }

    float scale = (sel == 0) ? QSCALE : 1.0f;   // log2e/sqrt(D) folded into Q
    #pragma unroll
    for (int m = 0; m < 2; m++) {
        #pragma unroll
        for (int n = 0; n < 4; n++) {
            int c = cb + n * 16 + l15;
            float bv_ = bias[c];
            int h = c >> 5, d = c & 31;
            #pragma unroll
            for (int r = 0; r < 4; r++) {
                int row = r0 + m * 16 + lq * 4 + r;   // C/D: row=(l>>4)*4+reg, col=l&15
                int s = row >> 1, b = row & 1;
                ushort_t v = f2bfbits((acc[m][n][r] + bv_) * scale);
                dst[((size_t)(b * NHEAD + h) * SEQ + s) * HEAD + d] = v;
            }
        }
    }
}

// ---------------- V transpose: [bh][s][d] -> blocked Vt2[bh][kblk][32d][32s]
__global__ __launch_bounds__(256) void vtrans(const ushort_t* __restrict__ Vb,
                                              ushort_t* __restrict__ Vt2)
{
    __shared__ ushort_t t[HEAD][65];
    int g = blockIdx.x;
    int bh = g & 15, st = g >> 4;       // 32 tiles of 64 s
    int s0 = st * 64;
    int tid = threadIdx.x;
    #pragma unroll
    for (int i = 0; i < 8; i++) {
        int idx = i * 256 + tid;
        int sl = idx >> 5, d = idx & 31;
        t[d][sl] = Vb[((size_t)bh * SEQ + s0 + sl) * HEAD + d];
    }
    __syncthreads();
    #pragma unroll
    for (int i = 0; i < 8; i++) {
        int idx = i * 256 + tid;
        int kb_l = idx >> 10, rem = idx & 1023;
        int d = rem >> 5, si = rem & 31;
        Vt2[(((size_t)bh * 64 + (s0 >> 5) + kb_l) * 32 + d) * 32 + si] = t[d][kb_l * 32 + si];
    }
}

// ---------------- Flash attention: 32x32 MFMA, zero-LDS main loop ----------
// (unchanged from R7 -- measured ~10us)
__global__ __launch_bounds__(256, 4) void attn(
    const ushort_t* __restrict__ Qb, const ushort_t* __restrict__ Kb,
    const ushort_t* __restrict__ Vt2, const float* __restrict__ mask,
    const unsigned long long* __restrict__ flagsG, float* __restrict__ out)
{
    int g  = blockIdx.x;
    int qt = g >> 4;              // 0..63 (32-row tiles)
    int b  = (g >> 3) & 1;
    int h  = g & 7;
    int bh = b * NHEAD + h;
    int w  = threadIdx.x >> 6;
    int l  = threadIdx.x & 63;
    int l31 = l & 31, hi = l >> 5;
    int qs0 = qt * 32;

    __shared__ float oacc[4][32][36];
    __shared__ float om[4][32], ol[4][32];

    const ushort_t* qrow = Qb + ((size_t)bh * SEQ + qs0 + l31) * HEAD + hi * 8;
    bf16x8 qf0 = *(const bf16x8*)(qrow);        // d 0..15 fragment
    bf16x8 qf1 = *(const bf16x8*)(qrow + 16);   // d 16..31

    unsigned long long fbits = flagsG[b * 128 + qt * 2] | flagsG[b * 128 + qt * 2 + 1];

    f32x16 acc = {};
    float mrun = -1e30f, lsum = 0.f;            // per-lane, q = l31

    int k0 = w * (SEQ / 4);
    const ushort_t* kbase = Kb  + ((size_t)bh * SEQ + k0 + l31) * HEAD + hi * 8;
    const ushort_t* vbase = Vt2 + ((size_t)bh * 64 + (k0 >> 5)) * 1024 + l31 * 32 + hi * 8;

    bf16x8 kc0 = *(const bf16x8*)(kbase);
    bf16x8 kc1 = *(const bf16x8*)(kbase + 16);
    bf16x8 vc0 = *(const bf16x8*)(vbase);
    bf16x8 vc1 = *(const bf16x8*)(vbase + 16);

    const int NT = (SEQ / 4) / 32;   // 16 tiles per wave
    for (int kt = 0; kt < NT; kt++) {
        int ktn = (kt + 1 < NT) ? kt + 1 : 0;   // wrap: prefetch discarded
        f32x16 st = {};
        st = __builtin_amdgcn_mfma_f32_32x32x16_bf16(kc0, qf0, st, 0, 0, 0);
        st = __builtin_amdgcn_mfma_f32_32x32x16_bf16(kc1, qf1, st, 0, 0, 0);

        bf16x8 kn0 = *(const bf16x8*)(kbase + ktn * 1024);
        bf16x8 kn1 = *(const bf16x8*)(kbase + ktn * 1024 + 16);
        bf16x8 vn0 = *(const bf16x8*)(vbase + ktn * 1024);
        bf16x8 vn1 = *(const bf16x8*)(vbase + ktn * 1024 + 16);

        if ((fbits >> (w * 16 + kt)) & 1ull) {   // nonzero mask tile: rare path
            const float* mr = mask + (size_t)b * SEQ * SEQ
                            + (size_t)(qs0 + l31) * SEQ + k0 + kt * 32 + hi * 4;
            union { float4 f4[4]; float f[16]; } mu;
            mu.f4[0] = *(const float4*)(mr);
            mu.f4[1] = *(const float4*)(mr + 8);
            mu.f4[2] = *(const float4*)(mr + 16);
            mu.f4[3] = *(const float4*)(mr + 24);
            #pragma unroll
            for (int j = 0; j < 16; j++) st[j] += mu.f[j] * LOG2E;
        }

        float x0 = fmaxf(st[0], st[1]),  x1 = fmaxf(st[2], st[3]);
        float x2 = fmaxf(st[4], st[5]),  x3 = fmaxf(st[6], st[7]);
        float x4 = fmaxf(st[8], st[9]),  x5 = fmaxf(st[10], st[11]);
        float x6 = fmaxf(st[12], st[13]), x7 = fmaxf(st[14], st[15]);
        float lmax = fmaxf(fmaxf(fmaxf(x0, x1), fmaxf(x2, x3)),
                           fmaxf(fmaxf(x4, x5), fmaxf(x6, x7)));

        if (__any(lmax > mrun + THRS)) {   // defer-max rescale (rare)
            v2i sw = __builtin_amdgcn_permlane32_swap(
                __float_as_int(lmax), __float_as_int(lmax), false, false);
            float pm = fmaxf(fmaxf(lmax, __int_as_float(sw.x)), __int_as_float(sw.y));
            float nm = fmaxf(mrun, pm);
            float sc = exp2a(mrun - nm);
            lsum *= sc;
            #pragma unroll
            for (int j = 0; j < 16; j++) acc[j] *= sc;   // q = own lane: no shuffle
            mrun = nm;
        }

        float ev[16];
        #pragma unroll
        for (int j = 0; j < 16; j++) ev[j] = exp2a(st[j] - mrun);
        lsum += (((ev[0]+ev[1])+(ev[2]+ev[3])) + ((ev[4]+ev[5])+(ev[6]+ev[7])))
              + (((ev[8]+ev[9])+(ev[10]+ev[11])) + ((ev[12]+ev[13])+(ev[14]+ev[15])));

        unsigned pk[8];
        #pragma unroll
        for (int j = 0; j < 8; j++) pk[j] = cvtpk(ev[2 * j], ev[2 * j + 1]);
        // P^T B-operand repack via permlane32_swap:
        //   new_a[l] = l<32 ? a[l] : b[l-32];  new_b[l] = l<32 ? a[l+32] : b[l]
        v2i p0 = __builtin_amdgcn_permlane32_swap((int)pk[0], (int)pk[2], false, false);
        v2i p1 = __builtin_amdgcn_permlane32_swap((int)pk[1], (int)pk[3], false, false);
        v2i p2 = __builtin_amdgcn_permlane32_swap((int)pk[4], (int)pk[6], false, false);
        v2i p3 = __builtin_amdgcn_permlane32_swap((int)pk[5], (int)pk[7], false, false);
        union { int i[4]; bf16x8 v; } pf0, pf1;
        pf0.i[0] = p0.x; pf0.i[1] = p1.x; pf0.i[2] = p0.y; pf0.i[3] = p1.y;
        pf1.i[0] = p2.x; pf1.i[1] = p3.x; pf1.i[2] = p2.y; pf1.i[3] = p3.y;

        acc = __builtin_amdgcn_mfma_f32_32x32x16_bf16(vc0, pf0.v, acc, 0, 0, 0);
        acc = __builtin_amdgcn_mfma_f32_32x32x16_bf16(vc1, pf1.v, acc, 0, 0, 0);

        kc0 = kn0; kc1 = kn1; vc0 = vn0; vc1 = vn1;
    }

    // lsum across the two half-lanes of each q
    v2i sl = __builtin_amdgcn_permlane32_swap(
        __float_as_int(lsum), __float_as_int(lsum), false, false);
    float lt = __int_as_float(sl.x) + __int_as_float(sl.y);
    if (hi == 0) { om[w][l31] = mrun; ol[w][l31] = lt; }

    #pragma unroll
    for (int gg = 0; gg < 4; gg++) {    // acc reg 4g+j -> d = j + 8g + 4hi
        f32x4 vv = { acc[4*gg], acc[4*gg+1], acc[4*gg+2], acc[4*gg+3] };
        *(f32x4*)&oacc[w][l31][8 * gg + 4 * hi] = vv;
    }
    __syncthreads();

    // merge 4 k-quarters: 1024 outputs, one float4 per thread
    int t = threadIdx.x;
    int q = t >> 3, d4 = (t & 7) * 4;
    float m0 = om[0][q], m1 = om[1][q], m2 = om[2][q], m3 = om[3][q];
    float mg = fmaxf(fmaxf(m0, m1), fmaxf(m2, m3));
    float w0_ = exp2a(m0 - mg), w1_ = exp2a(m1 - mg);
    float w2_ = exp2a(m2 - mg), w3_ = exp2a(m3 - mg);
    float lg = w0_ * ol[0][q] + w1_ * ol[1][q] + w2_ * ol[2][q] + w3_ * ol[3][q];
    float inv = 1.0f / lg;
    float4 o;
    o.x = (w0_*oacc[0][q][d4]   + w1_*oacc[1][q][d4]   + w2_*oacc[2][q][d4]   + w3_*oacc[3][q][d4])   * inv;
    o.y = (w0_*oacc[0][q][d4+1] + w1_*oacc[1][q][d4+1] + w2_*oacc[2][q][d4+1] + w3_*oacc[3][q][d4+1]) * inv;
    o.z = (w0_*oacc[0][q][d4+2] + w1_*oacc[1][q][d4+2] + w2_*oacc[2][q][d4+2] + w3_*oacc[3][q][d4+2]) * inv;
    o.w = (w0_*oacc[0][q][d4+3] + w1_*oacc[1][q][d4+3] + w2_*oacc[2][q][d4+3] + w3_*oacc[3][q][d4+3]) * inv;
    *(float4*)(out + ((size_t)(qs0 + q) * BATCH + b) * EMS + h * HEAD + d4) = o;
}

extern "C" void kernel_launch(void* const* d_in, const int* in_sizes, int n_in,
                              void* d_out, int out_size, void* d_ws, size_t ws_size,
                              hipStream_t stream) {
    const float* em  = (const float*)d_in[0];
    const float* mask = (const float*)d_in[1];
    const float* Wq  = (const float*)d_in[2];
    const float* bq  = (const float*)d_in[3];
    const float* Wk  = (const float*)d_in[4];
    const float* bk  = (const float*)d_in[5];
    const float* Wv  = (const float*)d_in[6];
    const float* bv  = (const float*)d_in[7];
    float* out = (float*)d_out;

    ushort_t* Qb  = (ushort_t*)d_ws;                      // [BH][S][D] bf16, 2MB
    ushort_t* Kb  = Qb + (size_t)BH * SEQ * HEAD;         // 2MB
    ushort_t* Vb  = Kb + (size_t)BH * SEQ * HEAD;         // 2MB
    ushort_t* Vt2 = Vb + (size_t)BH * SEQ * HEAD;         // [BH][64][32d][32s] bf16, 2MB
    unsigned* flagsG = (unsigned*)(Vt2 + (size_t)BH * SEQ * HEAD);  // 2KB

    fused_pre<<<dim3(896), dim3(256), 0, stream>>>(em, mask, Wq, bq, Wk, bk, Wv, bv,
                                                   Qb, Kb, Vb, flagsG);
    vtrans<<<dim3(512), dim3(256), 0, stream>>>(Vb, Vt2);
    attn<<<dim3(1024), dim3(256), 0, stream>>>(Qb, Kb, Vt2, mask,
                                               (const unsigned long long*)flagsG, out);
}